// Round 8
// baseline (280.839 us; speedup 1.0000x reference)
//
#include <hip/hip_runtime.h>

#define TT 512
#define BB 256
#define DIN 128
#define DH 128
#define PFD 8   // prefetch depth (steps); 2*PFD volatile loads in flight

typedef __attribute__((ext_vector_type(8))) short bf16x8;  // 8 bf16 in 4 VGPRs
typedef __attribute__((ext_vector_type(4))) float f32x4;

// ---------------------------------------------------------------------------
// Math simplification (exact, from the reference):
//   gates are [B,1] scalars broadcast over D_H and cx starts at 0, so the
//   whole state per (t,b) is two scalars (h, c):
//     z_j  = zx[t,b,j] + h * swh_j            (j = 28 gate/qubit slots)
//     p_g  = prod_{q=1..7} cos(z_{g,q})
//     f,i,o = sigmoid(p); u = tanh(p)
//     c = f*c + i*u ;  h = o*tanh(c)
//   outs[t,b,:] = h broadcast over 128; qw* are analytically dead.
// zx is a skinny GEMM [131072 x 128] @ [128 x 32] -> MFMA bf16 with hi/lo
// split (3 MFMA terms) for fp32-grade accuracy.
// seq: VOLATILE register prefetch ring (builtin ext-vector type, so volatile
// 16B loads are legal and single-instruction). Volatile loads keep their
// program position and stay compiler-visible, so SIInsertWaitcnts emits
// exact staggered vmcnt(N) waits before each use. h is staged in LDS to keep
// the per-step VMEM queue loads-only and make the final h_buf dump coalesced.
// ---------------------------------------------------------------------------

// ws layout (floats):
//   zxb  [TT*BB*32]  : x-projection + bias, slot = gate*8 + (q-1); slot 7 = 0
//   h_buf[TT*BB]     : h(t,b)   (also absorbs seq's harmless prefetch overread)
//   c_buf[BB]        : final c(b)
//   swh  [32]        : row-sums of the hx-half of W rows
//   bias32[32]       : bias per slot (0 in slots 7/15/23/31)
//   wbh/wbl          : B-fragment-packed bf16 hi/lo of W x-half, 4096 ushort each

__device__ __forceinline__ unsigned short f2bf(float x) {
    unsigned u = __float_as_uint(x);
    return (unsigned short)((u + 0x7fffu + ((u >> 16) & 1u)) >> 16);  // RNE
}

// ---- prep: pack W into B-fragments + bias32 + swh --------------------------
__global__ __launch_bounds__(256) void qlstm_prep(
    const float* __restrict__ Wf, const float* __restrict__ bf,
    const float* __restrict__ Wi, const float* __restrict__ bi,
    const float* __restrict__ Wu, const float* __restrict__ bu,
    const float* __restrict__ Wo, const float* __restrict__ bo,
    float* __restrict__ swh, float* __restrict__ bias32,
    unsigned short* __restrict__ wbh, unsigned short* __restrict__ wbl)
{
    int tid = threadIdx.x;
    // W fragments: element (nt,s,lane,j): n = nt*16+(lane&15), k = s*32+(lane>>4)*8+j
    for (int e = tid; e < 4096; e += 256) {
        int j    = e & 7;
        int lane = (e >> 3) & 63;
        int s    = (e >> 9) & 3;
        int nt   = e >> 11;
        int n    = nt * 16 + (lane & 15);
        int k    = s * 32 + (lane >> 4) * 8 + j;
        int g    = n >> 3;
        int qi   = n & 7;
        const float* W = (g == 0) ? Wf : ((g == 1) ? Wi : ((g == 2) ? Wu : Wo));
        float val = (qi < 7) ? W[(qi + 1) * 256 + k] : 0.f;
        unsigned short h = f2bf(val);
        wbh[e] = h;
        float hf = __uint_as_float(((unsigned)h) << 16);
        wbl[e] = f2bf(val - hf);
    }
    if (tid < 32) {
        int g = tid >> 3, qi = tid & 7;
        const float* bp = (g == 0) ? bf : ((g == 1) ? bi : ((g == 2) ? bu : bo));
        bias32[tid] = (qi < 7) ? bp[qi + 1] : 0.f;
    }
    {
        int slot = tid >> 3, sfx = tid & 7;
        int g = slot >> 3, qi = slot & 7;
        const float* W = (g == 0) ? Wf : ((g == 1) ? Wi : ((g == 2) ? Wu : Wo));
        float p = 0.f;
        if (qi < 7) {
            const float* row = W + (qi + 1) * 256 + 128 + sfx * 16;
#pragma unroll
            for (int k = 0; k < 16; ++k) p += row[k];
        }
        p += __shfl_xor(p, 1);
        p += __shfl_xor(p, 2);
        p += __shfl_xor(p, 4);
        if (sfx == 0) swh[slot] = p;   // qi==7 -> 0 (neutral)
    }
}

// ---- zx: MFMA GEMM  zxb[row][slot] = X[row] . W_slot + bias ----------------
__global__ __launch_bounds__(256) void qlstm_zx(
    const float* __restrict__ X,            // [TT*BB][128]
    const unsigned short* __restrict__ wbh,
    const unsigned short* __restrict__ wbl,
    const float* __restrict__ bias32,
    float* __restrict__ zxb)                // [TT*BB][32]
{
    int tid  = threadIdx.x;
    int w    = tid >> 6;
    int lane = tid & 63;
    int r    = lane & 15;
    int hi   = lane >> 4;
    long rowbase = (long)blockIdx.x * 64 + w * 16;

    float b0 = bias32[r], b1 = bias32[16 + r];
    f32x4 acc0 = {b0, b0, b0, b0};
    f32x4 acc1 = {b1, b1, b1, b1};

    const float* xrow = X + (rowbase + r) * 128 + hi * 8;
#pragma unroll
    for (int s = 0; s < 4; ++s) {
        float4 xa = *(const float4*)(xrow + s * 32);
        float4 xb = *(const float4*)(xrow + s * 32 + 4);
        float xs[8] = {xa.x, xa.y, xa.z, xa.w, xb.x, xb.y, xb.z, xb.w};
        bf16x8 ah, al;
#pragma unroll
        for (int j = 0; j < 8; ++j) {
            unsigned short hh = f2bf(xs[j]);
            ah[j] = (short)hh;
            float hf = __uint_as_float(((unsigned)hh) << 16);
            al[j] = (short)f2bf(xs[j] - hf);
        }
        bf16x8 bh0 = *(const bf16x8*)(wbh + ((size_t)(0 * 4 + s) * 64 + lane) * 8);
        bf16x8 bl0 = *(const bf16x8*)(wbl + ((size_t)(0 * 4 + s) * 64 + lane) * 8);
        bf16x8 bh1 = *(const bf16x8*)(wbh + ((size_t)(1 * 4 + s) * 64 + lane) * 8);
        bf16x8 bl1 = *(const bf16x8*)(wbl + ((size_t)(1 * 4 + s) * 64 + lane) * 8);
        acc0 = __builtin_amdgcn_mfma_f32_16x16x32_bf16(ah, bh0, acc0, 0, 0, 0);
        acc0 = __builtin_amdgcn_mfma_f32_16x16x32_bf16(al, bh0, acc0, 0, 0, 0);
        acc0 = __builtin_amdgcn_mfma_f32_16x16x32_bf16(ah, bl0, acc0, 0, 0, 0);
        acc1 = __builtin_amdgcn_mfma_f32_16x16x32_bf16(ah, bh1, acc1, 0, 0, 0);
        acc1 = __builtin_amdgcn_mfma_f32_16x16x32_bf16(al, bh1, acc1, 0, 0, 0);
        acc1 = __builtin_amdgcn_mfma_f32_16x16x32_bf16(ah, bl1, acc1, 0, 0, 0);
    }
    // C/D layout (m89-verified): col = lane&15, row = (lane>>4)*4 + reg
    float* zr = zxb + rowbase * 32;
#pragma unroll
    for (int reg = 0; reg < 4; ++reg) {
        int row = hi * 4 + reg;
        zr[row * 32 + r]      = acc0[reg];
        zr[row * 32 + 16 + r] = acc1[reg];
    }
}

// ---- sequential core: volatile register prefetch, 4 lanes per chain --------
template <int K>
__device__ __forceinline__ float quad_bcast(float v) {
    return __int_as_float(__builtin_amdgcn_mov_dpp(
        __float_as_int(v), K * 0x55, 0xf, 0xf, true));
}

__global__ __launch_bounds__(64) void qlstm_seq(
    const float* __restrict__ zxb,  // [TT*BB][32]
    const float* __restrict__ swh,  // [32]
    float* __restrict__ h_buf,      // [TT][BB]
    float* __restrict__ c_buf)      // [BB]
{
    __shared__ float lds_h[TT][16];            // 32 KB: h per (t, chain)
    int lane = threadIdx.x;                    // 64 = one wave
    int b0   = blockIdx.x * 16;
    int chn  = lane >> 2;                      // chain 0..15 within block
    int g    = lane & 3;                       // 0=f 1=i 2=u 3=o
    float4 s0 = *(const float4*)(swh + g * 8);
    float4 s1 = *(const float4*)(swh + g * 8 + 4);   // s1.w unused (slot 7)
    const float a    = (g == 2) ? 2.f : -1.f;  // exp arg scale: tanh vs sigmoid
    const bool  lead = (g == 0);
    const bool  isU  = (g == 2);

    // Volatile prefetch ring, depth PFD (builtin ext-vector => volatile 16B
    // loads are legal, single global_load_dwordx4). Volatile loads hold their
    // program position (issue PFD steps ahead of use); SIInsertWaitcnts emits
    // the exact staggered vmcnt(N) before each use. Last chunk overreads
    // <= PFD steps past zxb's end -> lands inside h_buf (256 KB of 512 KB
    // used), values discarded -> safe.
    const volatile f32x4* vp =
        (const volatile f32x4*)(zxb + (size_t)(b0 + chn) * 32 + g * 8);
    f32x4 bufA[PFD], bufB[PFD];
#pragma unroll
    for (int d = 0; d < PFD; ++d) {
        bufA[d] = vp[0];
        bufB[d] = vp[1];
        vp += BB * 8;                          // BB*32 floats = BB*8 f32x4s
    }

    float h = 0.f, c = 0.f;
#pragma unroll 1
    for (int chk = 0; chk < TT / PFD; ++chk) {
#pragma unroll
        for (int d = 0; d < PFD; ++d) {
            int t = chk * PFD + d;
            f32x4 cur0 = bufA[d];
            f32x4 cur1 = bufB[d];
            bufA[d] = vp[0];                   // prefetch step t+PFD
            bufB[d] = vp[1];
            vp += BB * 8;

            float z0 = fmaf(h, s0.x, cur0[0]);
            float z1 = fmaf(h, s0.y, cur0[1]);
            float z2 = fmaf(h, s0.z, cur0[2]);
            float z3 = fmaf(h, s0.w, cur0[3]);
            float z4 = fmaf(h, s1.x, cur1[0]);
            float z5 = fmaf(h, s1.y, cur1[1]);
            float z6 = fmaf(h, s1.z, cur1[2]);
            float q0 = __cosf(z0), q1 = __cosf(z1), q2 = __cosf(z2), q3 = __cosf(z3);
            float q4 = __cosf(z4), q5 = __cosf(z5), q6 = __cosf(z6);
            float pr = ((q0 * q1) * (q2 * q3)) * ((q4 * q5) * q6);
            // sigmoid(x)=1/(1+e^-x); tanh(x)=1-2/(e^{2x}+1)
            float E  = __expf(a * pr);
            float rc = __builtin_amdgcn_rcpf(1.f + E);
            float val = isU ? fmaf(-2.f, rc, 1.f) : rc;
            float f_ = quad_bcast<0>(val);
            float i_ = quad_bcast<1>(val);
            float u_ = quad_bcast<2>(val);
            float o_ = quad_bcast<3>(val);
            c = fmaf(f_, c, i_ * u_);
            float E2 = __expf(2.f * c);
            float th = fmaf(-2.f, __builtin_amdgcn_rcpf(1.f + E2), 1.f);
            h = o_ * th;
            if (lead) lds_h[t][chn] = h;       // ds_write: lgkmcnt domain only
        }
    }
    if (lead) c_buf[b0 + chn] = c;

    // dump lds_h -> h_buf, coalesced float4 per lane (single wave: LDS ops
    // complete in order; compiler inserts the lgkmcnt waits)
    __builtin_amdgcn_s_waitcnt(0);             // belt-and-braces drain
    int tq = lane >> 2;                        // 0..15
    int jj = lane & 3;
#pragma unroll 4
    for (int t0 = 0; t0 < TT; t0 += 16) {
        int t = t0 + tq;
        float4 v = *(const float4*)&lds_h[t][jj * 4];
        *(float4*)&h_buf[(size_t)t * BB + b0 + jj * 4] = v;
    }
}

// ---- broadcast h(t,b) into the [T,B,128] output + final (hx,cx) ------------
__global__ __launch_bounds__(256) void qlstm_bcast(
    const float* __restrict__ h_buf, const float* __restrict__ c_buf,
    float4* __restrict__ out4)
{
    const int N1 = TT * BB * 32;       // outs region in float4s
    const int N2 = N1 + BB * 32;       // + final hx
    const int N3 = N2 + BB * 32;       // + final cx
    int stride = gridDim.x * blockDim.x;
    for (int i = blockIdx.x * blockDim.x + threadIdx.x; i < N3; i += stride) {
        float v;
        if (i < N1)      v = h_buf[i >> 5];
        else if (i < N2) v = h_buf[(TT - 1) * BB + ((i - N1) >> 5)];
        else             v = c_buf[(i - N2) >> 5];
        out4[i] = make_float4(v, v, v, v);
    }
}

extern "C" void kernel_launch(void* const* d_in, const int* in_sizes, int n_in,
                              void* d_out, int out_size, void* d_ws, size_t ws_size,
                              hipStream_t stream)
{
    const float* X  = (const float*)d_in[0];
    const float* Wf = (const float*)d_in[1];
    const float* bf = (const float*)d_in[2];
    const float* Wi = (const float*)d_in[3];
    const float* bi = (const float*)d_in[4];
    const float* Wu = (const float*)d_in[5];
    const float* bu = (const float*)d_in[6];
    const float* Wo = (const float*)d_in[7];
    const float* bo = (const float*)d_in[8];
    // d_in[9..12] = qwf/qwi/qwu/qwo: analytically unused.

    float* ws    = (float*)d_ws;
    float* zxb   = ws;                                  // 16.78 MB
    float* h_buf = ws + (size_t)TT * BB * 32;           // 0.52 MB
    float* c_buf = h_buf + (size_t)TT * BB;             // 1 KB
    float* swh   = c_buf + BB;                          // 128 B
    float* bias32 = swh + 32;                           // 128 B
    unsigned short* wbh = (unsigned short*)(bias32 + 32);  // 8 KB
    unsigned short* wbl = wbh + 4096;                      // 8 KB

    qlstm_prep<<<1, 256, 0, stream>>>(Wf, bf, Wi, bi, Wu, bu, Wo, bo,
                                      swh, bias32, wbh, wbl);
    qlstm_zx<<<TT * BB / 64, 256, 0, stream>>>(X, wbh, wbl, bias32, zxb);
    qlstm_seq<<<BB / 16, 64, 0, stream>>>(zxb, swh, h_buf, c_buf);
    qlstm_bcast<<<4096, 256, 0, stream>>>(h_buf, c_buf, (float4*)d_out);
}

// Round 9
// 136.152 us; speedup vs baseline: 2.0627x; 2.0627x over previous
//
#include <hip/hip_runtime.h>

#define TT 512
#define BB 256
#define DIN 128
#define DH 128

typedef __attribute__((ext_vector_type(8))) short bf16x8;  // 8 bf16 in 4 VGPRs
typedef __attribute__((ext_vector_type(4))) float f32x4;

// ---------------------------------------------------------------------------
// Math simplification (exact, from the reference):
//   gates are [B,1] scalars broadcast over D_H and cx starts at 0, so the
//   whole state per (t,b) is two scalars (h, c):
//     z_j  = zx[t,b,j] + h * swh_j            (j = 28 gate/qubit slots)
//     p_g  = prod_{q=1..7} cos(z_{g,q})
//     f,i,o = sigmoid(p); u = tanh(p)
//     c = f*c + i*u ;  h = o*tanh(c)
//   outs[t,b,:] = h broadcast over 128; qw* are analytically dead.
// zx is a skinny GEMM [131072 x 128] @ [128 x 32] -> MFMA bf16 with hi/lo
// split (3 MFMA terms), output TRANSPOSED to [b][t][32] so each chain's
// stream is contiguous.
// seq (fused): per block = one chain. Phase 1: 256 threads coalesce-load the
// chain's whole 64 KB zxb stream into LDS. Phase 2: 4 lanes walk the 512-step
// recurrence reading LDS only (1-step register prefetch; no global memory in
// the loop -> nothing for the compiler to mis-schedule). Phase 3: all 256
// threads broadcast lds_h into the [T,B,128] output + final hx/cx.
// ---------------------------------------------------------------------------

// ws layout (floats):
//   zxbT [BB*TT*32]  : x-projection + bias, [b][t][slot]; slot 7/15/23/31 = 0
//   swh  [32]        : row-sums of the hx-half of W rows
//   bias32[32]       : bias per slot
//   wbh/wbl          : B-fragment-packed bf16 hi/lo of W x-half, 4096 ushort each

__device__ __forceinline__ unsigned short f2bf(float x) {
    unsigned u = __float_as_uint(x);
    return (unsigned short)((u + 0x7fffu + ((u >> 16) & 1u)) >> 16);  // RNE
}

// ---- prep: pack W into B-fragments + bias32 + swh --------------------------
__global__ __launch_bounds__(256) void qlstm_prep(
    const float* __restrict__ Wf, const float* __restrict__ bf,
    const float* __restrict__ Wi, const float* __restrict__ bi,
    const float* __restrict__ Wu, const float* __restrict__ bu,
    const float* __restrict__ Wo, const float* __restrict__ bo,
    float* __restrict__ swh, float* __restrict__ bias32,
    unsigned short* __restrict__ wbh, unsigned short* __restrict__ wbl)
{
    int tid = threadIdx.x;
    // W fragments: element (nt,s,lane,j): n = nt*16+(lane&15), k = s*32+(lane>>4)*8+j
    for (int e = tid; e < 4096; e += 256) {
        int j    = e & 7;
        int lane = (e >> 3) & 63;
        int s    = (e >> 9) & 3;
        int nt   = e >> 11;
        int n    = nt * 16 + (lane & 15);
        int k    = s * 32 + (lane >> 4) * 8 + j;
        int g    = n >> 3;
        int qi   = n & 7;
        const float* W = (g == 0) ? Wf : ((g == 1) ? Wi : ((g == 2) ? Wu : Wo));
        float val = (qi < 7) ? W[(qi + 1) * 256 + k] : 0.f;
        unsigned short h = f2bf(val);
        wbh[e] = h;
        float hf = __uint_as_float(((unsigned)h) << 16);
        wbl[e] = f2bf(val - hf);
    }
    if (tid < 32) {
        int g = tid >> 3, qi = tid & 7;
        const float* bp = (g == 0) ? bf : ((g == 1) ? bi : ((g == 2) ? bu : bo));
        bias32[tid] = (qi < 7) ? bp[qi + 1] : 0.f;
    }
    {
        int slot = tid >> 3, sfx = tid & 7;
        int g = slot >> 3, qi = slot & 7;
        const float* W = (g == 0) ? Wf : ((g == 1) ? Wi : ((g == 2) ? Wu : Wo));
        float p = 0.f;
        if (qi < 7) {
            const float* row = W + (qi + 1) * 256 + 128 + sfx * 16;
#pragma unroll
            for (int k = 0; k < 16; ++k) p += row[k];
        }
        p += __shfl_xor(p, 1);
        p += __shfl_xor(p, 2);
        p += __shfl_xor(p, 4);
        if (sfx == 0) swh[slot] = p;   // qi==7 -> 0 (neutral)
    }
}

// ---- zx: MFMA GEMM  zxbT[b][t][slot] = X[t*BB+b] . W_slot + bias -----------
__global__ __launch_bounds__(256) void qlstm_zx(
    const float* __restrict__ X,            // [TT*BB][128]
    const unsigned short* __restrict__ wbh,
    const unsigned short* __restrict__ wbl,
    const float* __restrict__ bias32,
    float* __restrict__ zxbT)               // [BB][TT][32]
{
    int tid  = threadIdx.x;
    int w    = tid >> 6;
    int lane = tid & 63;
    int r    = lane & 15;
    int hi   = lane >> 4;
    long rowbase = (long)blockIdx.x * 64 + w * 16;

    float b0 = bias32[r], b1 = bias32[16 + r];
    f32x4 acc0 = {b0, b0, b0, b0};
    f32x4 acc1 = {b1, b1, b1, b1};

    const float* xrow = X + (rowbase + r) * 128 + hi * 8;
#pragma unroll
    for (int s = 0; s < 4; ++s) {
        float4 xa = *(const float4*)(xrow + s * 32);
        float4 xb = *(const float4*)(xrow + s * 32 + 4);
        float xs[8] = {xa.x, xa.y, xa.z, xa.w, xb.x, xb.y, xb.z, xb.w};
        bf16x8 ah, al;
#pragma unroll
        for (int j = 0; j < 8; ++j) {
            unsigned short hh = f2bf(xs[j]);
            ah[j] = (short)hh;
            float hf = __uint_as_float(((unsigned)hh) << 16);
            al[j] = (short)f2bf(xs[j] - hf);
        }
        bf16x8 bh0 = *(const bf16x8*)(wbh + ((size_t)(0 * 4 + s) * 64 + lane) * 8);
        bf16x8 bl0 = *(const bf16x8*)(wbl + ((size_t)(0 * 4 + s) * 64 + lane) * 8);
        bf16x8 bh1 = *(const bf16x8*)(wbh + ((size_t)(1 * 4 + s) * 64 + lane) * 8);
        bf16x8 bl1 = *(const bf16x8*)(wbl + ((size_t)(1 * 4 + s) * 64 + lane) * 8);
        acc0 = __builtin_amdgcn_mfma_f32_16x16x32_bf16(ah, bh0, acc0, 0, 0, 0);
        acc0 = __builtin_amdgcn_mfma_f32_16x16x32_bf16(al, bh0, acc0, 0, 0, 0);
        acc0 = __builtin_amdgcn_mfma_f32_16x16x32_bf16(ah, bl0, acc0, 0, 0, 0);
        acc1 = __builtin_amdgcn_mfma_f32_16x16x32_bf16(ah, bh1, acc1, 0, 0, 0);
        acc1 = __builtin_amdgcn_mfma_f32_16x16x32_bf16(al, bh1, acc1, 0, 0, 0);
        acc1 = __builtin_amdgcn_mfma_f32_16x16x32_bf16(ah, bl1, acc1, 0, 0, 0);
    }
    // C/D layout (m89-verified): col = lane&15, row = (lane>>4)*4 + reg
#pragma unroll
    for (int reg = 0; reg < 4; ++reg) {
        long rowidx = rowbase + hi * 4 + reg;      // global row = t*BB + b
        int  bb = (int)(rowidx & 255);
        int  tt = (int)(rowidx >> 8);
        float* addr = zxbT + ((size_t)bb * TT + tt) * 32;
        addr[r]      = acc0[reg];
        addr[16 + r] = acc1[reg];
    }
}

// ---- fused sequential core + broadcast: one chain per block ----------------
template <int K>
__device__ __forceinline__ float quad_bcast(float v) {
    return __int_as_float(__builtin_amdgcn_mov_dpp(
        __float_as_int(v), K * 0x55, 0xf, 0xf, true));
}

__global__ __launch_bounds__(256) void qlstm_seq(
    const float* __restrict__ zxbT,  // [BB][TT][32]
    const float* __restrict__ swh,   // [32]
    float* __restrict__ out)         // outs [TT*BB*128] | hx [BB*128] | cx [BB*128]
{
    __shared__ float lds_z[TT * 32];   // 64 KB: this chain's zx stream
    __shared__ float lds_h[TT];        // 2 KB : h(t)
    __shared__ float lds_c;            // final c
    int tid = threadIdx.x;
    int b   = blockIdx.x;

    // Phase 1: coalesced load of the chain's whole stream into LDS
    {
        const float4* src = (const float4*)(zxbT + (size_t)b * TT * 32);
        float4* dst = (float4*)lds_z;
#pragma unroll
        for (int i = 0; i < (TT * 32 / 4) / 256; ++i)   // 16 iters
            dst[tid + i * 256] = src[tid + i * 256];
    }
    __syncthreads();

    // Phase 2: 4 lanes walk the recurrence; LDS-only, 1-step register prefetch
    if (tid < 4) {
        int g = tid;                               // 0=f 1=i 2=u 3=o
        float4 s0 = *(const float4*)(swh + g * 8);
        float4 s1 = *(const float4*)(swh + g * 8 + 4);   // s1.w unused (slot 7)
        const float a    = (g == 2) ? 2.f : -1.f;  // exp arg scale
        const bool  lead = (g == 0);
        const bool  isU  = (g == 2);

        const float* lp0 = lds_z + g * 8;
        float4 nx0 = *(const float4*)(lp0);
        float4 nx1 = *(const float4*)(lp0 + 4);
        float h = 0.f, c = 0.f;
#pragma unroll 8
        for (int t = 0; t < TT; ++t) {
            float4 cur0 = nx0;
            float4 cur1 = nx1;
            const float* lpn = lds_z + ((t + 1) & (TT - 1)) * 32 + g * 8;
            nx0 = *(const float4*)(lpn);       // prefetch next step (t=511
            nx1 = *(const float4*)(lpn + 4);   //  wraps to t=0, discarded)
            float z0 = fmaf(h, s0.x, cur0.x);
            float z1 = fmaf(h, s0.y, cur0.y);
            float z2 = fmaf(h, s0.z, cur0.z);
            float z3 = fmaf(h, s0.w, cur0.w);
            float z4 = fmaf(h, s1.x, cur1.x);
            float z5 = fmaf(h, s1.y, cur1.y);
            float z6 = fmaf(h, s1.z, cur1.z);
            float q0 = __cosf(z0), q1 = __cosf(z1), q2 = __cosf(z2), q3 = __cosf(z3);
            float q4 = __cosf(z4), q5 = __cosf(z5), q6 = __cosf(z6);
            float pr = ((q0 * q1) * (q2 * q3)) * ((q4 * q5) * q6);
            // sigmoid(x)=1/(1+e^-x); tanh(x)=1-2/(e^{2x}+1)
            float E  = __expf(a * pr);
            float rc = __builtin_amdgcn_rcpf(1.f + E);
            float val = isU ? fmaf(-2.f, rc, 1.f) : rc;
            float f_ = quad_bcast<0>(val);
            float i_ = quad_bcast<1>(val);
            float u_ = quad_bcast<2>(val);
            float o_ = quad_bcast<3>(val);
            c = fmaf(f_, c, i_ * u_);
            float E2 = __expf(2.f * c);
            float th = fmaf(-2.f, __builtin_amdgcn_rcpf(1.f + E2), 1.f);
            h = o_ * th;
            if (lead) lds_h[t] = h;
        }
        if (lead) lds_c = c;
    }
    __syncthreads();

    // Phase 3: broadcast h(t) into out[t][b][0..127] (+ final hx/cx)
    {
        float4* out4 = (float4*)out;
        int tq = tid >> 5;             // 0..7: which t within a group of 8
        int e  = tid & 31;             // float4 index within the 128-elem row
#pragma unroll 4
        for (int t0 = 0; t0 < TT; t0 += 8) {
            int t = t0 + tq;
            float hv = lds_h[t];
            float4 v = make_float4(hv, hv, hv, hv);
            out4[((size_t)t * BB + b) * 32 + e] = v;
        }
        float hN = lds_h[TT - 1];
        float cN = lds_c;
        size_t base = (size_t)TT * BB * 32;
        if (tid < 32) {
            out4[base + (size_t)b * 32 + tid] = make_float4(hN, hN, hN, hN);
        } else if (tid < 64) {
            out4[base + (size_t)BB * 32 + (size_t)b * 32 + (tid - 32)] =
                make_float4(cN, cN, cN, cN);
        }
    }
}

extern "C" void kernel_launch(void* const* d_in, const int* in_sizes, int n_in,
                              void* d_out, int out_size, void* d_ws, size_t ws_size,
                              hipStream_t stream)
{
    const float* X  = (const float*)d_in[0];
    const float* Wf = (const float*)d_in[1];
    const float* bf = (const float*)d_in[2];
    const float* Wi = (const float*)d_in[3];
    const float* bi = (const float*)d_in[4];
    const float* Wu = (const float*)d_in[5];
    const float* bu = (const float*)d_in[6];
    const float* Wo = (const float*)d_in[7];
    const float* bo = (const float*)d_in[8];
    // d_in[9..12] = qwf/qwi/qwu/qwo: analytically unused.

    float* ws     = (float*)d_ws;
    float* zxbT   = ws;                                 // 16.78 MB
    float* swh    = ws + (size_t)BB * TT * 32;          // 128 B
    float* bias32 = swh + 32;                           // 128 B
    unsigned short* wbh = (unsigned short*)(bias32 + 32);  // 8 KB
    unsigned short* wbl = wbh + 4096;                      // 8 KB

    qlstm_prep<<<1, 256, 0, stream>>>(Wf, bf, Wi, bi, Wu, bu, Wo, bo,
                                      swh, bias32, wbh, wbl);
    qlstm_zx<<<TT * BB / 64, 256, 0, stream>>>(X, wbh, wbl, bias32, zxbT);
    qlstm_seq<<<BB, 256, 0, stream>>>(zxbT, swh, (float*)d_out);
}

// Round 10
// 135.292 us; speedup vs baseline: 2.0758x; 1.0064x over previous
//
#include <hip/hip_runtime.h>

#define TT 512
#define BB 256
#define DIN 128
#define DH 128

typedef __attribute__((ext_vector_type(8))) short bf16x8;  // 8 bf16 in 4 VGPRs
typedef __attribute__((ext_vector_type(4))) float f32x4;

// ---------------------------------------------------------------------------
// Math simplification (exact, from the reference):
//   gates are [B,1] scalars broadcast over D_H and cx starts at 0, so the
//   whole state per (t,b) is two scalars (h, c):
//     z_j  = zx[t,b,j] + h * swh_j            (j = 28 gate/qubit slots)
//     p_g  = prod_{q=1..7} cos(z_{g,q})
//     f,i,o = sigmoid(p); u = tanh(p)
//     c = f*c + i*u ;  h = o*tanh(c)
//   outs[t,b,:] = h broadcast over 128; qw* are analytically dead.
//
// seq phase-2 nonlinearity chain is transcendental-minimal:
//   T = tanh(pr/2)   deg-9 odd Taylor (|pr|<=1 -> arg<=0.5, err 4e-6)
//   sigma(pr) = 0.5 + 0.5*T                          (exact identity)
//   tanh(pr)  = 2T/(1+T^2), 1/(1+w) deg-4 series     (w<=0.214, err 3.7e-4)
//   tanh(c)   = Pade[7/6], one v_rcp                 (|c|<=2.1, err ~1e-5)
//   cos via raw v_cos builtin (arg in revolutions, |arg|<2 << HW domain)
// ---------------------------------------------------------------------------

// ws layout (floats):
//   zxbT [BB*TT*32]  : x-projection + bias, [b][t][slot]; slot 7/15/23/31 = 0
//   swh  [32]        : row-sums of the hx-half of W rows
//   bias32[32]       : bias per slot
//   wbh/wbl          : B-fragment-packed bf16 hi/lo of W x-half, 4096 ushort each

__device__ __forceinline__ unsigned short f2bf(float x) {
    unsigned u = __float_as_uint(x);
    return (unsigned short)((u + 0x7fffu + ((u >> 16) & 1u)) >> 16);  // RNE
}

// ---- prep: pack W into B-fragments + bias32 + swh --------------------------
__global__ __launch_bounds__(256) void qlstm_prep(
    const float* __restrict__ Wf, const float* __restrict__ bf,
    const float* __restrict__ Wi, const float* __restrict__ bi,
    const float* __restrict__ Wu, const float* __restrict__ bu,
    const float* __restrict__ Wo, const float* __restrict__ bo,
    float* __restrict__ swh, float* __restrict__ bias32,
    unsigned short* __restrict__ wbh, unsigned short* __restrict__ wbl)
{
    int tid = threadIdx.x;
    // W fragments: element (nt,s,lane,j): n = nt*16+(lane&15), k = s*32+(lane>>4)*8+j
    for (int e = tid; e < 4096; e += 256) {
        int j    = e & 7;
        int lane = (e >> 3) & 63;
        int s    = (e >> 9) & 3;
        int nt   = e >> 11;
        int n    = nt * 16 + (lane & 15);
        int k    = s * 32 + (lane >> 4) * 8 + j;
        int g    = n >> 3;
        int qi   = n & 7;
        const float* W = (g == 0) ? Wf : ((g == 1) ? Wi : ((g == 2) ? Wu : Wo));
        float val = (qi < 7) ? W[(qi + 1) * 256 + k] : 0.f;
        unsigned short h = f2bf(val);
        wbh[e] = h;
        float hf = __uint_as_float(((unsigned)h) << 16);
        wbl[e] = f2bf(val - hf);
    }
    if (tid < 32) {
        int g = tid >> 3, qi = tid & 7;
        const float* bp = (g == 0) ? bf : ((g == 1) ? bi : ((g == 2) ? bu : bo));
        bias32[tid] = (qi < 7) ? bp[qi + 1] : 0.f;
    }
    {
        int slot = tid >> 3, sfx = tid & 7;
        int g = slot >> 3, qi = slot & 7;
        const float* W = (g == 0) ? Wf : ((g == 1) ? Wi : ((g == 2) ? Wu : Wo));
        float p = 0.f;
        if (qi < 7) {
            const float* row = W + (qi + 1) * 256 + 128 + sfx * 16;
#pragma unroll
            for (int k = 0; k < 16; ++k) p += row[k];
        }
        p += __shfl_xor(p, 1);
        p += __shfl_xor(p, 2);
        p += __shfl_xor(p, 4);
        if (sfx == 0) swh[slot] = p;   // qi==7 -> 0 (neutral)
    }
}

// ---- zx: MFMA GEMM  zxbT[b][t][slot] = X[t*BB+b] . W_slot + bias -----------
__global__ __launch_bounds__(256) void qlstm_zx(
    const float* __restrict__ X,            // [TT*BB][128]
    const unsigned short* __restrict__ wbh,
    const unsigned short* __restrict__ wbl,
    const float* __restrict__ bias32,
    float* __restrict__ zxbT)               // [BB][TT][32]
{
    int tid  = threadIdx.x;
    int w    = tid >> 6;
    int lane = tid & 63;
    int r    = lane & 15;
    int hi   = lane >> 4;
    long rowbase = (long)blockIdx.x * 64 + w * 16;

    float b0 = bias32[r], b1 = bias32[16 + r];
    f32x4 acc0 = {b0, b0, b0, b0};
    f32x4 acc1 = {b1, b1, b1, b1};

    const float* xrow = X + (rowbase + r) * 128 + hi * 8;
#pragma unroll
    for (int s = 0; s < 4; ++s) {
        float4 xa = *(const float4*)(xrow + s * 32);
        float4 xb = *(const float4*)(xrow + s * 32 + 4);
        float xs[8] = {xa.x, xa.y, xa.z, xa.w, xb.x, xb.y, xb.z, xb.w};
        bf16x8 ah, al;
#pragma unroll
        for (int j = 0; j < 8; ++j) {
            unsigned short hh = f2bf(xs[j]);
            ah[j] = (short)hh;
            float hf = __uint_as_float(((unsigned)hh) << 16);
            al[j] = (short)f2bf(xs[j] - hf);
        }
        bf16x8 bh0 = *(const bf16x8*)(wbh + ((size_t)(0 * 4 + s) * 64 + lane) * 8);
        bf16x8 bl0 = *(const bf16x8*)(wbl + ((size_t)(0 * 4 + s) * 64 + lane) * 8);
        bf16x8 bh1 = *(const bf16x8*)(wbh + ((size_t)(1 * 4 + s) * 64 + lane) * 8);
        bf16x8 bl1 = *(const bf16x8*)(wbl + ((size_t)(1 * 4 + s) * 64 + lane) * 8);
        acc0 = __builtin_amdgcn_mfma_f32_16x16x32_bf16(ah, bh0, acc0, 0, 0, 0);
        acc0 = __builtin_amdgcn_mfma_f32_16x16x32_bf16(al, bh0, acc0, 0, 0, 0);
        acc0 = __builtin_amdgcn_mfma_f32_16x16x32_bf16(ah, bl0, acc0, 0, 0, 0);
        acc1 = __builtin_amdgcn_mfma_f32_16x16x32_bf16(ah, bh1, acc1, 0, 0, 0);
        acc1 = __builtin_amdgcn_mfma_f32_16x16x32_bf16(al, bh1, acc1, 0, 0, 0);
        acc1 = __builtin_amdgcn_mfma_f32_16x16x32_bf16(ah, bl1, acc1, 0, 0, 0);
    }
    // C/D layout (m89-verified): col = lane&15, row = (lane>>4)*4 + reg
#pragma unroll
    for (int reg = 0; reg < 4; ++reg) {
        long rowidx = rowbase + hi * 4 + reg;      // global row = t*BB + b
        int  bb = (int)(rowidx & 255);
        int  tt = (int)(rowidx >> 8);
        float* addr = zxbT + ((size_t)bb * TT + tt) * 32;
        addr[r]      = acc0[reg];
        addr[16 + r] = acc1[reg];
    }
}

// ---- fused sequential core + broadcast: one chain per block ----------------
template <int K>
__device__ __forceinline__ float quad_bcast(float v) {
    return __int_as_float(__builtin_amdgcn_mov_dpp(
        __float_as_int(v), K * 0x55, 0xf, 0xf, true));
}

__global__ __launch_bounds__(256) void qlstm_seq(
    const float* __restrict__ zxbT,  // [BB][TT][32]
    const float* __restrict__ swh,   // [32]
    float* __restrict__ out)         // outs [TT*BB*128] | hx [BB*128] | cx [BB*128]
{
    __shared__ float lds_z[TT * 32];   // 64 KB: this chain's zx stream
    __shared__ float lds_h[TT];        // 2 KB : h(t)
    __shared__ float lds_c;            // final c
    int tid = threadIdx.x;
    int b   = blockIdx.x;

    // Phase 1: coalesced load of the chain's whole stream into LDS
    {
        const float4* src = (const float4*)(zxbT + (size_t)b * TT * 32);
        float4* dst = (float4*)lds_z;
#pragma unroll
        for (int i = 0; i < (TT * 32 / 4) / 256; ++i)   // 16 iters
            dst[tid + i * 256] = src[tid + i * 256];
    }
    __syncthreads();

    // Phase 2: 4 lanes walk the recurrence; LDS-only, 1-step register prefetch
    if (tid < 4) {
        int g = tid;                               // 0=f 1=i 2=u 3=o
        float4 s0 = *(const float4*)(swh + g * 8);
        float4 s1 = *(const float4*)(swh + g * 8 + 4);   // s1.w unused (slot 7)
        const bool isU = (g == 2);
        const float INV2PI = 0.15915494309189535f;

        const float* lp0 = lds_z + g * 8;
        float4 nx0 = *(const float4*)(lp0);
        float4 nx1 = *(const float4*)(lp0 + 4);
        float h = 0.f, c = 0.f;
#pragma unroll 8
        for (int t = 0; t < TT; ++t) {
            float4 cur0 = nx0;
            float4 cur1 = nx1;
            const float* lpn = lds_z + ((t + 1) & (TT - 1)) * 32 + g * 8;
            nx0 = *(const float4*)(lpn);       // prefetch next step (t=511
            nx1 = *(const float4*)(lpn + 4);   //  wraps to t=0, discarded)
            float z0 = fmaf(h, s0.x, cur0.x);
            float z1 = fmaf(h, s0.y, cur0.y);
            float z2 = fmaf(h, s0.z, cur0.z);
            float z3 = fmaf(h, s0.w, cur0.w);
            float z4 = fmaf(h, s1.x, cur1.x);
            float z5 = fmaf(h, s1.y, cur1.y);
            float z6 = fmaf(h, s1.z, cur1.z);
            // native v_cos, input in revolutions (|z|<~8 rad -> |rev|<~1.3,
            // well inside HW domain; no reduction needed)
            float q0 = __builtin_amdgcn_cosf(z0 * INV2PI);
            float q1 = __builtin_amdgcn_cosf(z1 * INV2PI);
            float q2 = __builtin_amdgcn_cosf(z2 * INV2PI);
            float q3 = __builtin_amdgcn_cosf(z3 * INV2PI);
            float q4 = __builtin_amdgcn_cosf(z4 * INV2PI);
            float q5 = __builtin_amdgcn_cosf(z5 * INV2PI);
            float q6 = __builtin_amdgcn_cosf(z6 * INV2PI);
            float pr = ((q0 * q1) * (q2 * q3)) * ((q4 * q5) * q6);

            // T = tanh(pr/2), deg-9 odd Taylor (arg <= 0.5, err ~4e-6)
            float v = 0.5f * pr;
            float y = v * v;
            float tp = fmaf(y, 0.021869489f, -0.053968254f);
            tp = fmaf(y, tp, 0.13333333f);
            tp = fmaf(y, tp, -0.33333333f);
            float T = v * fmaf(y, tp, 1.0f);
            // sigma(pr) = 0.5 + 0.5T ; tanh(pr) = 2T/(1+T^2), 1/(1+w) deg-4
            float w = T * T;
            float rr = 1.f - w;
            rr = fmaf(-w, rr, 1.f);
            rr = fmaf(-w, rr, 1.f);
            rr = fmaf(-w, rr, 1.f);
            float vu = (2.f * T) * rr;
            float vf = fmaf(0.5f, T, 0.5f);
            float val = isU ? vu : vf;

            float f_ = quad_bcast<0>(val);
            float i_ = quad_bcast<1>(val);
            float u_ = quad_bcast<2>(val);
            float o_ = quad_bcast<3>(val);
            c = fmaf(f_, c, i_ * u_);

            // tanh(c) Pade[7/6]: c(135135+17325y+378y^2+y^3) /
            //                    (135135+62370y+3150y^2+28y^3)
            float yc = c * c;
            float dn = fmaf(yc, 28.f, 3150.f);
            dn = fmaf(yc, dn, 62370.f);
            dn = fmaf(yc, dn, 135135.f);
            float nm = yc + 378.f;
            nm = fmaf(yc, nm, 17325.f);
            nm = fmaf(yc, nm, 135135.f);
            nm *= c;
            float th = nm * __builtin_amdgcn_rcpf(dn);
            h = o_ * th;
            lds_h[t] = h;                      // 4 lanes, same value/addr
        }
        lds_c = c;
    }
    __syncthreads();

    // Phase 3: broadcast h(t) into out[t][b][0..127] (+ final hx/cx)
    {
        float4* out4 = (float4*)out;
        int tq = tid >> 5;             // 0..7: which t within a group of 8
        int e  = tid & 31;             // float4 index within the 128-elem row
#pragma unroll 4
        for (int t0 = 0; t0 < TT; t0 += 8) {
            int t = t0 + tq;
            float hv = lds_h[t];
            float4 v = make_float4(hv, hv, hv, hv);
            out4[((size_t)t * BB + b) * 32 + e] = v;
        }
        float hN = lds_h[TT - 1];
        float cN = lds_c;
        size_t base = (size_t)TT * BB * 32;
        if (tid < 32) {
            out4[base + (size_t)b * 32 + tid] = make_float4(hN, hN, hN, hN);
        } else if (tid < 64) {
            out4[base + (size_t)BB * 32 + (size_t)b * 32 + (tid - 32)] =
                make_float4(cN, cN, cN, cN);
        }
    }
}

extern "C" void kernel_launch(void* const* d_in, const int* in_sizes, int n_in,
                              void* d_out, int out_size, void* d_ws, size_t ws_size,
                              hipStream_t stream)
{
    const float* X  = (const float*)d_in[0];
    const float* Wf = (const float*)d_in[1];
    const float* bf = (const float*)d_in[2];
    const float* Wi = (const float*)d_in[3];
    const float* bi = (const float*)d_in[4];
    const float* Wu = (const float*)d_in[5];
    const float* bu = (const float*)d_in[6];
    const float* Wo = (const float*)d_in[7];
    const float* bo = (const float*)d_in[8];
    // d_in[9..12] = qwf/qwi/qwu/qwo: analytically unused.

    float* ws     = (float*)d_ws;
    float* zxbT   = ws;                                 // 16.78 MB
    float* swh    = ws + (size_t)BB * TT * 32;          // 128 B
    float* bias32 = swh + 32;                           // 128 B
    unsigned short* wbh = (unsigned short*)(bias32 + 32);  // 8 KB
    unsigned short* wbl = wbh + 4096;                      // 8 KB

    qlstm_prep<<<1, 256, 0, stream>>>(Wf, bf, Wi, bi, Wu, bu, Wo, bo,
                                      swh, bias32, wbh, wbl);
    qlstm_zx<<<TT * BB / 64, 256, 0, stream>>>(X, wbh, wbl, bias32, zxbT);
    qlstm_seq<<<BB, 256, 0, stream>>>(zxbT, swh, (float*)d_out);
}

// Round 11
// 131.591 us; speedup vs baseline: 2.1342x; 1.0281x over previous
//
#include <hip/hip_runtime.h>

#define TT 512
#define BB 256
#define DIN 128
#define DH 128

typedef __attribute__((ext_vector_type(8))) short bf16x8;  // 8 bf16 in 4 VGPRs
typedef __attribute__((ext_vector_type(4))) float f32x4;

// ---------------------------------------------------------------------------
// Math simplification (exact, from the reference):
//   gates are [B,1] scalars broadcast over D_H and cx starts at 0, so the
//   whole state per (t,b) is two scalars (h, c):
//     z_j  = zx[t,b,j] + h * swh_j            (j = 28 gate/qubit slots)
//     p_g  = prod_{q=1..7} cos(z_{g,q})
//     f,i,o = sigmoid(p); u = tanh(p)
//     c = f*c + i*u ;  h = o*tanh(c)
//   outs[t,b,:] = h broadcast over 128; qw* are analytically dead.
//
// R10 post-mortem: exp-chain (R9) vs poly-chain (R10) changed nothing ->
// phase 2 is NOT arithmetic-composition-bound; the exposed ds_read latency
// (compiler sinks the "prefetch" to its use) + serial chain sets ~470cy/step.
// This round: loads issued at top of body + sched_barrier(0) pins them above
// the math (load-to-use = full body, ~120cy ds_read latency hidden), and the
// chain is shortened: zx/swh prescaled by 1/2pi (cos takes revolutions
// directly) and gates/tanh via v_exp_f32 (exp2) on premultiplied args.
// ---------------------------------------------------------------------------

// ws layout (floats):
//   zxbT [BB*TT*32]  : (x-proj + bias) * INV2PI, [b][t][slot]; slots 7/15/23/31 = 0
//   swh  [32]        : row-sums of hx-half of W rows, * INV2PI
//   bias32[32]       : bias per slot
//   wbh/wbl          : B-fragment-packed bf16 hi/lo of W x-half, 4096 ushort each

#define INV2PI 0.15915494309189535f

__device__ __forceinline__ unsigned short f2bf(float x) {
    unsigned u = __float_as_uint(x);
    return (unsigned short)((u + 0x7fffu + ((u >> 16) & 1u)) >> 16);  // RNE
}

__device__ __forceinline__ float exp2_hw(float x) {   // v_exp_f32: 2^x
    float r;
    asm("v_exp_f32 %0, %1" : "=v"(r) : "v"(x));
    return r;
}

// ---- prep: pack W into B-fragments + bias32 + swh --------------------------
__global__ __launch_bounds__(256) void qlstm_prep(
    const float* __restrict__ Wf, const float* __restrict__ bf,
    const float* __restrict__ Wi, const float* __restrict__ bi,
    const float* __restrict__ Wu, const float* __restrict__ bu,
    const float* __restrict__ Wo, const float* __restrict__ bo,
    float* __restrict__ swh, float* __restrict__ bias32,
    unsigned short* __restrict__ wbh, unsigned short* __restrict__ wbl)
{
    int tid = threadIdx.x;
    // W fragments: element (nt,s,lane,j): n = nt*16+(lane&15), k = s*32+(lane>>4)*8+j
    for (int e = tid; e < 4096; e += 256) {
        int j    = e & 7;
        int lane = (e >> 3) & 63;
        int s    = (e >> 9) & 3;
        int nt   = e >> 11;
        int n    = nt * 16 + (lane & 15);
        int k    = s * 32 + (lane >> 4) * 8 + j;
        int g    = n >> 3;
        int qi   = n & 7;
        const float* W = (g == 0) ? Wf : ((g == 1) ? Wi : ((g == 2) ? Wu : Wo));
        float val = (qi < 7) ? W[(qi + 1) * 256 + k] : 0.f;
        unsigned short h = f2bf(val);
        wbh[e] = h;
        float hf = __uint_as_float(((unsigned)h) << 16);
        wbl[e] = f2bf(val - hf);
    }
    if (tid < 32) {
        int g = tid >> 3, qi = tid & 7;
        const float* bp = (g == 0) ? bf : ((g == 1) ? bi : ((g == 2) ? bu : bo));
        bias32[tid] = (qi < 7) ? bp[qi + 1] : 0.f;
    }
    {
        int slot = tid >> 3, sfx = tid & 7;
        int g = slot >> 3, qi = slot & 7;
        const float* W = (g == 0) ? Wf : ((g == 1) ? Wi : ((g == 2) ? Wu : Wo));
        float p = 0.f;
        if (qi < 7) {
            const float* row = W + (qi + 1) * 256 + 128 + sfx * 16;
#pragma unroll
            for (int k = 0; k < 16; ++k) p += row[k];
        }
        p += __shfl_xor(p, 1);
        p += __shfl_xor(p, 2);
        p += __shfl_xor(p, 4);
        if (sfx == 0) swh[slot] = p * INV2PI;   // pre-scaled to revolutions
    }
}

// ---- zx: MFMA GEMM  zxbT[b][t][slot] = (X[t*BB+b].W_slot + bias)*INV2PI ----
__global__ __launch_bounds__(256) void qlstm_zx(
    const float* __restrict__ X,            // [TT*BB][128]
    const unsigned short* __restrict__ wbh,
    const unsigned short* __restrict__ wbl,
    const float* __restrict__ bias32,
    float* __restrict__ zxbT)               // [BB][TT][32]
{
    int tid  = threadIdx.x;
    int w    = tid >> 6;
    int lane = tid & 63;
    int r    = lane & 15;
    int hi   = lane >> 4;
    long rowbase = (long)blockIdx.x * 64 + w * 16;

    float b0 = bias32[r], b1 = bias32[16 + r];
    f32x4 acc0 = {b0, b0, b0, b0};
    f32x4 acc1 = {b1, b1, b1, b1};

    const float* xrow = X + (rowbase + r) * 128 + hi * 8;
#pragma unroll
    for (int s = 0; s < 4; ++s) {
        float4 xa = *(const float4*)(xrow + s * 32);
        float4 xb = *(const float4*)(xrow + s * 32 + 4);
        float xs[8] = {xa.x, xa.y, xa.z, xa.w, xb.x, xb.y, xb.z, xb.w};
        bf16x8 ah, al;
#pragma unroll
        for (int j = 0; j < 8; ++j) {
            unsigned short hh = f2bf(xs[j]);
            ah[j] = (short)hh;
            float hf = __uint_as_float(((unsigned)hh) << 16);
            al[j] = (short)f2bf(xs[j] - hf);
        }
        bf16x8 bh0 = *(const bf16x8*)(wbh + ((size_t)(0 * 4 + s) * 64 + lane) * 8);
        bf16x8 bl0 = *(const bf16x8*)(wbl + ((size_t)(0 * 4 + s) * 64 + lane) * 8);
        bf16x8 bh1 = *(const bf16x8*)(wbh + ((size_t)(1 * 4 + s) * 64 + lane) * 8);
        bf16x8 bl1 = *(const bf16x8*)(wbl + ((size_t)(1 * 4 + s) * 64 + lane) * 8);
        acc0 = __builtin_amdgcn_mfma_f32_16x16x32_bf16(ah, bh0, acc0, 0, 0, 0);
        acc0 = __builtin_amdgcn_mfma_f32_16x16x32_bf16(al, bh0, acc0, 0, 0, 0);
        acc0 = __builtin_amdgcn_mfma_f32_16x16x32_bf16(ah, bl0, acc0, 0, 0, 0);
        acc1 = __builtin_amdgcn_mfma_f32_16x16x32_bf16(ah, bh1, acc1, 0, 0, 0);
        acc1 = __builtin_amdgcn_mfma_f32_16x16x32_bf16(al, bh1, acc1, 0, 0, 0);
        acc1 = __builtin_amdgcn_mfma_f32_16x16x32_bf16(ah, bl1, acc1, 0, 0, 0);
    }
    // C/D layout (m89-verified): col = lane&15, row = (lane>>4)*4 + reg
#pragma unroll
    for (int reg = 0; reg < 4; ++reg) {
        long rowidx = rowbase + hi * 4 + reg;      // global row = t*BB + b
        int  bb = (int)(rowidx & 255);
        int  tt = (int)(rowidx >> 8);
        float* addr = zxbT + ((size_t)bb * TT + tt) * 32;
        addr[r]      = acc0[reg] * INV2PI;
        addr[16 + r] = acc1[reg] * INV2PI;
    }
}

// ---- fused sequential core + broadcast: one chain per block ----------------
template <int K>
__device__ __forceinline__ float quad_bcast(float v) {
    return __int_as_float(__builtin_amdgcn_mov_dpp(
        __float_as_int(v), K * 0x55, 0xf, 0xf, true));
}

__global__ __launch_bounds__(256) void qlstm_seq(
    const float* __restrict__ zxbT,  // [BB][TT][32], rev-scaled
    const float* __restrict__ swh,   // [32], rev-scaled
    float* __restrict__ out)         // outs [TT*BB*128] | hx [BB*128] | cx [BB*128]
{
    __shared__ float lds_z[TT * 32];   // 64 KB: this chain's zx stream
    __shared__ float lds_h[TT];        // 2 KB : h(t)
    __shared__ float lds_c;            // final c
    int tid = threadIdx.x;
    int b   = blockIdx.x;

    // Phase 1: coalesced load of the chain's whole stream into LDS
    {
        const float4* src = (const float4*)(zxbT + (size_t)b * TT * 32);
        float4* dst = (float4*)lds_z;
#pragma unroll
        for (int i = 0; i < (TT * 32 / 4) / 256; ++i)   // 16 iters
            dst[tid + i * 256] = src[tid + i * 256];
    }
    __syncthreads();

    // Phase 2: 4 lanes walk the recurrence; loads issued at top of body and
    // pinned above the math by sched_barrier(0) -> load-to-use = full body,
    // ds_read latency hidden. Last iteration's prefetch reads into lds_h
    // (within allocation), values discarded -> safe.
    if (tid < 4) {
        int g = tid;                               // 0=f 1=i 2=u 3=o
        float4 s0 = *(const float4*)(swh + g * 8);
        float4 s1 = *(const float4*)(swh + g * 8 + 4);   // s1.w unused (slot 7)
        const bool  isU = (g == 2);
        // exp2 arg scale: sigmoid: 2^(-pr*log2e); tanh: 2^(2pr*log2e)
        const float al = isU ? 2.885390081777927f : -1.4426950408889634f;

        const float* lp0 = lds_z + g * 8;
        f32x4 nx0 = *(const f32x4*)(lp0);
        f32x4 nx1 = *(const f32x4*)(lp0 + 4);
        float h = 0.f, c = 0.f;
#pragma unroll 2
        for (int t = 0; t < TT; ++t) {
            f32x4 cur0 = nx0;
            f32x4 cur1 = nx1;
            const float* lpn = lds_z + (t + 1) * 32 + g * 8;
            nx0 = *(const f32x4*)(lpn);        // prefetch step t+1
            nx1 = *(const f32x4*)(lpn + 4);
            __builtin_amdgcn_sched_barrier(0); // loads may not sink below
            float z0 = fmaf(h, s0.x, cur0[0]);
            float z1 = fmaf(h, s0.y, cur0[1]);
            float z2 = fmaf(h, s0.z, cur0[2]);
            float z3 = fmaf(h, s0.w, cur0[3]);
            float z4 = fmaf(h, s1.x, cur1[0]);
            float z5 = fmaf(h, s1.y, cur1[1]);
            float z6 = fmaf(h, s1.z, cur1[2]);
            // native v_cos, args already in revolutions (|z_rev| < ~1.5)
            float q0 = __builtin_amdgcn_cosf(z0);
            float q1 = __builtin_amdgcn_cosf(z1);
            float q2 = __builtin_amdgcn_cosf(z2);
            float q3 = __builtin_amdgcn_cosf(z3);
            float q4 = __builtin_amdgcn_cosf(z4);
            float q5 = __builtin_amdgcn_cosf(z5);
            float q6 = __builtin_amdgcn_cosf(z6);
            float pr = ((q0 * q1) * (q2 * q3)) * ((q4 * q5) * q6);
            // sigmoid(x)=1/(1+2^(-x log2e)); tanh(x)=1-2/(1+2^(2x log2e))
            float E  = exp2_hw(pr * al);
            float rc = __builtin_amdgcn_rcpf(1.f + E);
            float val = isU ? fmaf(-2.f, rc, 1.f) : rc;
            float f_ = quad_bcast<0>(val);
            float i_ = quad_bcast<1>(val);
            float u_ = quad_bcast<2>(val);
            float o_ = quad_bcast<3>(val);
            c = fmaf(f_, c, i_ * u_);
            float E2 = exp2_hw(c * 2.885390081777927f);
            float th = fmaf(-2.f, __builtin_amdgcn_rcpf(1.f + E2), 1.f);
            h = o_ * th;
            lds_h[t] = h;                      // 4 lanes, same value/addr
        }
        lds_c = c;
    }
    __syncthreads();

    // Phase 3: broadcast h(t) into out[t][b][0..127] (+ final hx/cx)
    {
        float4* out4 = (float4*)out;
        int tq = tid >> 5;             // 0..7: which t within a group of 8
        int e  = tid & 31;             // float4 index within the 128-elem row
#pragma unroll 4
        for (int t0 = 0; t0 < TT; t0 += 8) {
            int t = t0 + tq;
            float hv = lds_h[t];
            float4 v = make_float4(hv, hv, hv, hv);
            out4[((size_t)t * BB + b) * 32 + e] = v;
        }
        float hN = lds_h[TT - 1];
        float cN = lds_c;
        size_t base = (size_t)TT * BB * 32;
        if (tid < 32) {
            out4[base + (size_t)b * 32 + tid] = make_float4(hN, hN, hN, hN);
        } else if (tid < 64) {
            out4[base + (size_t)BB * 32 + (size_t)b * 32 + (tid - 32)] =
                make_float4(cN, cN, cN, cN);
        }
    }
}

extern "C" void kernel_launch(void* const* d_in, const int* in_sizes, int n_in,
                              void* d_out, int out_size, void* d_ws, size_t ws_size,
                              hipStream_t stream)
{
    const float* X  = (const float*)d_in[0];
    const float* Wf = (const float*)d_in[1];
    const float* bf = (const float*)d_in[2];
    const float* Wi = (const float*)d_in[3];
    const float* bi = (const float*)d_in[4];
    const float* Wu = (const float*)d_in[5];
    const float* bu = (const float*)d_in[6];
    const float* Wo = (const float*)d_in[7];
    const float* bo = (const float*)d_in[8];
    // d_in[9..12] = qwf/qwi/qwu/qwo: analytically unused.

    float* ws     = (float*)d_ws;
    float* zxbT   = ws;                                 // 16.78 MB
    float* swh    = ws + (size_t)BB * TT * 32;          // 128 B
    float* bias32 = swh + 32;                           // 128 B
    unsigned short* wbh = (unsigned short*)(bias32 + 32);  // 8 KB
    unsigned short* wbl = wbh + 4096;                      // 8 KB

    qlstm_prep<<<1, 256, 0, stream>>>(Wf, bf, Wi, bi, Wu, bu, Wo, bo,
                                      swh, bias32, wbh, wbl);
    qlstm_zx<<<TT * BB / 64, 256, 0, stream>>>(X, wbh, wbl, bias32, zxbT);
    qlstm_seq<<<BB, 256, 0, stream>>>(zxbT, swh, (float*)d_out);
}